// Round 5
// baseline (81460.028 us; speedup 1.0000x reference)
//
#include <hip/hip_runtime.h>
#include <hip/hip_bf16.h>
#include <stdint.h>

// ---------------------------------------------------------------------------
// Bidirectional 5-layer LSTM (all-sigmoid), B=16, T=1024, D=1024, U=512.
// R7: XCD-pinned L2-local h exchange on top of the R3 structure.
//   - 256 blocks launched; roles (dir,slice) claimed at runtime: per-XCD
//     pools via s_getreg(HW_REG_XCC_ID) (XCD0=fwd, XCD1=bwd), CAS-owned role
//     table + slept fallback scan guarantees all 32 roles claimed exactly
//     once regardless of XCC_ID behavior. Surplus blocks exit.
//   - One-time handshake publishes each role's XCD; mode = all-16-same-XCD,
//     computed identically by every block of the dir.
//   - Local mode: plain h stores (write-through L1 -> shared local L2, dirty)
//     + sc0 poll loads (L1-bypass, L2-served): ~200cy RT instead of ~900cy
//     LLC RT. Remote mode: R3's agent store + sc0 sc1 polls (safe fallback).
//   - Stale-L1 forward-progress guard: agent-acquire fence every 64th retry.
//   - Trailing per-step barrier dropped (sentinel dataflow + BAR1(s+1) order
//     all LDS reuse; poll includes own block's h so no wave runs ahead).
//     BAR1/BAR2 are lgkmcnt-only. xz prefetch issued after the poll so the
//     poll's vmcnt(0) never drains a fresh HBM load.
// ---------------------------------------------------------------------------

typedef __attribute__((ext_vector_type(8))) short short8;
typedef __attribute__((ext_vector_type(4))) float f32x4;

union U128 { uint4 u; short8 s; };
static __device__ __forceinline__ short8 as_short8(uint4 v) { U128 x; x.u = v; return x.s; }

static __device__ __forceinline__ float sigf(float x) { return 1.0f / (1.0f + __expf(-x)); }

static __device__ __forceinline__ uint32_t f2bfbits(float f) {
  union { float f; uint32_t u; } x; x.f = f;
  return (x.u + 0x7fffu + ((x.u >> 16) & 1u)) >> 16;   // RNE; h in (0,1), no NaN
}
static __device__ __forceinline__ float bflo(uint32_t v) {
  union { uint32_t u; float f; } x; x.u = v << 16; return x.f;
}
static __device__ __forceinline__ float bfhi(uint32_t v) {
  union { uint32_t u; float f; } x; x.u = v & 0xffff0000u; return x.f;
}

// poll loads: 4x16B, batched issue, one wait.
// sc0 = coherent/L1-bypass (serve from L2). sc0 sc1 = bypass L2 too (LLC).
static __device__ __forceinline__ void poll4_l2(const char* p0, const char* p1,
                                                const char* p2, const char* p3,
                                                uint4& a0, uint4& a1, uint4& a2, uint4& a3) {
  asm volatile(
      "global_load_dwordx4 %0, %4, off sc0\n\t"
      "global_load_dwordx4 %1, %5, off sc0\n\t"
      "global_load_dwordx4 %2, %6, off sc0\n\t"
      "global_load_dwordx4 %3, %7, off sc0\n\t"
      "s_waitcnt vmcnt(0)"
      : "=&v"(a0), "=&v"(a1), "=&v"(a2), "=&v"(a3)
      : "v"(p0), "v"(p1), "v"(p2), "v"(p3)
      : "memory");
}
static __device__ __forceinline__ void poll4_llc(const char* p0, const char* p1,
                                                 const char* p2, const char* p3,
                                                 uint4& a0, uint4& a1, uint4& a2, uint4& a3) {
  asm volatile(
      "global_load_dwordx4 %0, %4, off sc0 sc1\n\t"
      "global_load_dwordx4 %1, %5, off sc0 sc1\n\t"
      "global_load_dwordx4 %2, %6, off sc0 sc1\n\t"
      "global_load_dwordx4 %3, %7, off sc0 sc1\n\t"
      "s_waitcnt vmcnt(0)"
      : "=&v"(a0), "=&v"(a1), "=&v"(a2), "=&v"(a3)
      : "v"(p0), "v"(p1), "v"(p2), "v"(p3)
      : "memory");
}
static __device__ __forceinline__ bool ok16(const uint4& a, const uint4& b,
                                            const uint4& c, const uint4& d) {
  return a.x && a.y && a.z && a.w && b.x && b.y && b.z && b.w &&
         c.x && c.y && c.z && c.w && d.x && d.y && d.z && d.w;
}

// ---------------- x (fp32) -> bf16 ----------------
__global__ __launch_bounds__(256) void f32_to_bf16_k(const float* __restrict__ in,
                                                     __hip_bfloat16* __restrict__ out,
                                                     int n4) {
  int i = blockIdx.x * 256 + threadIdx.x;
  if (i < n4) {
    float4 v = ((const float4*)in)[i];
    uint32_t lo = f2bfbits(v.x) | (f2bfbits(v.y) << 16);
    uint32_t hi = f2bfbits(v.z) | (f2bfbits(v.w) << 16);
    ((uint2*)out)[i] = make_uint2(lo, hi);
  }
}

// ---------------- [2][R][2048] fp32 -> [2][2048][R] bf16 transpose ----------------
__global__ __launch_bounds__(256) void transpose_bf16_k(const float* __restrict__ in,
                                                        __hip_bfloat16* __restrict__ outp,
                                                        int R) {
  __shared__ float tile[64][65];
  int d = blockIdx.z;
  int k0 = blockIdx.x * 64;
  int c0 = blockIdx.y * 64;
  const float* inb = in + (size_t)d * R * 2048;
  __hip_bfloat16* ob = outp + (size_t)d * 2048 * R;
  int col = threadIdx.x & 63, rr = threadIdx.x >> 6;
#pragma unroll
  for (int i = 0; i < 16; ++i) {
    int r = rr + i * 4;
    tile[r][col] = inb[(size_t)(k0 + r) * 2048 + c0 + col];
  }
  __syncthreads();
#pragma unroll
  for (int i = 0; i < 16; ++i) {
    int r = rr + i * 4;
    ob[(size_t)(c0 + r) * R + k0 + col] = __float2bfloat16(tile[col][r]);
  }
}

// ---------------- xz GEMM: y[16384,1024] @ Wt[2][2048,1024]^T + b ----------------
// Output layout: xz[dir][swg(16)][t(1024)][q(4)][b(16)][j(32)]  (4KB per (dir,swg,t))
__global__ __launch_bounds__(256) void gemm_xz_k(const __hip_bfloat16* __restrict__ y,
                                                 const __hip_bfloat16* __restrict__ Wt,
                                                 const float* __restrict__ bias,
                                                 __hip_bfloat16* __restrict__ xz) {
  __shared__ uint4 Asl[8 * 2 * 64];
  __shared__ uint4 Bsl[8 * 2 * 64];
  int m0 = blockIdx.x * 128;
  int dir = blockIdx.y >> 4;
  int n0 = (blockIdx.y & 15) * 128;
  int tid = threadIdx.x, lane = tid & 63, wv = tid >> 6;
  int wm = wv & 1, wn = wv >> 1;
  const __hip_bfloat16* Wd = Wt + (size_t)dir * 2048 * 1024;
  f32x4 acc[4][4] = {};
  for (int kb = 0; kb < 1024; kb += 64) {
    __syncthreads();
#pragma unroll
    for (int i = 0; i < 4; ++i) {
      int slot = i * 256 + tid;
      int ln = slot & 63, kc = (slot >> 6) & 1, mt = slot >> 7;
      int row = mt * 16 + (ln & 15);
      int kk = kc * 32 + (ln >> 4) * 8;
      Asl[slot] = *(const uint4*)(y + (size_t)(m0 + row) * 1024 + kb + kk);
      Bsl[slot] = *(const uint4*)(Wd + (size_t)(n0 + row) * 1024 + kb + kk);
    }
    __syncthreads();
#pragma unroll
    for (int kc = 0; kc < 2; ++kc) {
      short8 af[4], bf[4];
#pragma unroll
      for (int i = 0; i < 4; ++i) {
        af[i] = as_short8(Asl[((wm * 4 + i) * 2 + kc) * 64 + lane]);
        bf[i] = as_short8(Bsl[((wn * 4 + i) * 2 + kc) * 64 + lane]);
      }
#pragma unroll
      for (int i = 0; i < 4; ++i)
#pragma unroll
        for (int j = 0; j < 4; ++j)
          acc[i][j] = __builtin_amdgcn_mfma_f32_16x16x32_bf16(af[i], bf[j], acc[i][j], 0, 0, 0);
    }
  }
  // epilogue: C/D layout col=lane&15, row=(lane>>4)*4+r  [m89-verified]
  int cq = lane >> 4, cn = lane & 15;
#pragma unroll
  for (int i = 0; i < 4; ++i)
#pragma unroll
    for (int j = 0; j < 4; ++j) {
      int n_g = n0 + (wn * 4 + j) * 16 + cn;
      int q = n_g >> 9, u = n_g & 511, swg = u >> 5, jj = u & 31;
      float bv = bias[dir * 2048 + n_g];
#pragma unroll
      for (int r = 0; r < 4; ++r) {
        int m = m0 + (wm * 4 + i) * 16 + cq * 4 + r;
        int b = m >> 10, t = m & 1023;
        size_t addr = (((size_t)(dir * 16 + swg) * 1024 + t) * 2048) + (q * 16 + b) * 32 + jj;
        xz[addr] = __float2bfloat16(acc[i][j][r] + bv);
      }
    }
}

// ---------------- persistent bidirectional recurrence ----------------
// 256 blocks launched; 32 claim roles (dir=role>>4, slice=role&15, 32 u-cols),
// rest exit. LDS: uh 128KB | hbuf 16x520 bf16 | zbuf 16x132 f32 | xbuf 2048
// bf16 | ctrl 2 ints  -> 160264 B.
__global__ __launch_bounds__(256) void lstm_rec_k(const __hip_bfloat16* __restrict__ Ut,  // [2][2048][512]
                                                  const __hip_bfloat16* __restrict__ xz,  // [dir][swg][t][2048]
                                                  __hip_bfloat16* __restrict__ ynext,     // [16][1024][1024], pre-zeroed
                                                  float* __restrict__ outf,               // last layer or null
                                                  int* __restrict__ claim) {              // [0..7]=cnt [8..39]=own [40..71]=xcc
  extern __shared__ char smem[];
  uint4* uh = (uint4*)smem;                                 // 8192 x 16B
  __hip_bfloat16* hbuf = (__hip_bfloat16*)(smem + 131072);  // [16][520]
  float* zbuf = (float*)(smem + 147712);                    // [16][132]
  __hip_bfloat16* xbuf = (__hip_bfloat16*)(smem + 156160);  // [2048]
  int* ctrl = (int*)(smem + 160256);                        // [role, mode]
  int tid = threadIdx.x, lane = tid & 63, wv = tid >> 6;
  int quad = lane >> 4, l15 = lane & 15;

  int* cnt = claim;
  int* own = claim + 8;
  int* cxc = claim + 40;

  // ---- role claiming ----
  if (tid == 0) {
    uint32_t xcc;
    asm volatile("s_getreg_b32 %0, hwreg(HW_REG_XCC_ID)" : "=s"(xcc));
    xcc &= 0xfu;
    int role = -1;
    if (xcc < 2u) {
      int c = atomicAdd(cnt + xcc, 1);
      if (c < 16) {
        int r = (int)xcc * 16 + c;
        if (atomicCAS(own + r, 0, 1) == 0) role = r;
      }
    }
    if (role < 0) {
      for (int i = 0; i < 8; ++i) asm volatile("s_sleep 127");   // ~27us: let primaries claim
      for (int r = 0; r < 32; ++r)
        if (atomicCAS(own + r, 0, 1) == 0) { role = r; break; }
    }
    if (role >= 0)
      __hip_atomic_store(cxc + role, (int)xcc + 1, __ATOMIC_RELAXED, __HIP_MEMORY_SCOPE_AGENT);
    ctrl[0] = role;
  }
  __syncthreads();
  int role = ctrl[0];
  if (role < 0) return;
  int dir = role >> 4, swg = role & 15;
  int u0 = swg * 32;
  const __hip_bfloat16* Ud = Ut + (size_t)dir * 2048 * 512;

  // ---- fill LDS with Uh slice, pre-fragmented (same as R3) ----
#pragma unroll 4
  for (int i = 0; i < 32; ++i) {
    int slot = i * 256 + tid;
    int ls = slot & 63, kc = (slot >> 6) & 15, nt = slot >> 10;
    int n_g = (nt >> 1) * 512 + u0 + (nt & 1) * 16 + (ls & 15);
    int k = kc * 32 + (ls >> 4) * 8;
    uh[slot] = *(const uint4*)(Ud + (size_t)n_g * 512 + k);
  }

  // ---- handshake: mode = all 16 same-dir roles on one XCD ----
  if (wv == 0) {
    int myv = 0;
    if (lane < 16) {
      const int* e = cxc + dir * 16 + lane;
      do {
        myv = __hip_atomic_load(e, __ATOMIC_RELAXED, __HIP_MEMORY_SCOPE_AGENT);
      } while (myv == 0);
    }
    int v0 = __shfl(myv, 0);
    int same = (lane < 16) ? (myv == v0) : 1;
    int allsame = __all(same);
    if (lane == 0) ctrl[1] = allsame;
  }
  __syncthreads();
  const int local = ctrl[1];   // 1 = shared-L2 fast path

  int nt0 = wv * 2, nt1 = wv * 2 + 1;
  int pb = tid >> 4, pj = (tid & 15) * 2;
  int brow = tid >> 6, col8 = (tid & 63) * 8;
  float c0 = 0.f, c1 = 0.f;

  int t0 = dir ? 1023 : 0;
  uint4 xcur = *((const uint4*)(xz + ((size_t)(dir * 16 + swg) * 1024 + t0) * 2048) + tid);

  for (int s = 0; s < 1024; ++s) {
    int t = dir ? (1023 - s) : s;
    f32x4 z0 = {}, z1 = {};
    uint4 xnxt = xcur;
    if (s > 0) {
      int tprev = dir ? (t + 1) : (t - 1);
      const char* p0 = (const char*)(ynext + ((size_t)(0 * 4 + brow) * 1024 + tprev) * 1024 + dir * 512 + col8);
      const char* p1 = (const char*)(ynext + ((size_t)(1 * 4 + brow) * 1024 + tprev) * 1024 + dir * 512 + col8);
      const char* p2 = (const char*)(ynext + ((size_t)(2 * 4 + brow) * 1024 + tprev) * 1024 + dir * 512 + col8);
      const char* p3 = (const char*)(ynext + ((size_t)(3 * 4 + brow) * 1024 + tprev) * 1024 + dir * 512 + col8);
      uint4 a0, a1, a2, a3;
      int tries = 0;
      for (;;) {
        if (local) poll4_l2(p0, p1, p2, p3, a0, a1, a2, a3);
        else       poll4_llc(p0, p1, p2, p3, a0, a1, a2, a3);
        if (ok16(a0, a1, a2, a3)) break;
        if (((++tries) & 63) == 0)
          __builtin_amdgcn_fence(__ATOMIC_ACQUIRE, "agent");  // stale-clean-line guard
      }
      // stage h -> hbuf
      *(uint4*)(hbuf + (0 * 4 + brow) * 520 + col8) = a0;
      *(uint4*)(hbuf + (1 * 4 + brow) * 520 + col8) = a1;
      *(uint4*)(hbuf + (2 * 4 + brow) * 520 + col8) = a2;
      *(uint4*)(hbuf + (3 * 4 + brow) * 520 + col8) = a3;
      // prefetch next xz AFTER the poll (so poll's vmcnt(0) never drains it)
      if (s < 1023) {
        int tn = dir ? (t - 1) : (t + 1);
        xnxt = *((const uint4*)(xz + ((size_t)(dir * 16 + swg) * 1024 + tn) * 2048) + tid);
      }
      // BAR1: LDS-only barrier
      asm volatile("s_waitcnt lgkmcnt(0)\ns_barrier" ::: "memory");
      // A-frags from LDS (b128) + MFMA
#pragma unroll
      for (int kc = 0; kc < 16; ++kc) {
        short8 afrag = *(const short8*)(hbuf + l15 * 520 + kc * 32 + quad * 8);
        z0 = __builtin_amdgcn_mfma_f32_16x16x32_bf16(afrag, as_short8(uh[(nt0 * 16 + kc) * 64 + lane]), z0, 0, 0, 0);
        z1 = __builtin_amdgcn_mfma_f32_16x16x32_bf16(afrag, as_short8(uh[(nt1 * 16 + kc) * 64 + lane]), z1, 0, 0, 0);
      }
    } else {
      int tn = dir ? (t - 1) : (t + 1);
      xnxt = *((const uint4*)(xz + ((size_t)(dir * 16 + swg) * 1024 + tn) * 2048) + tid);
    }
    // publish z to zbuf (pitch 132); stage xz chunk to xbuf
#pragma unroll
    for (int r = 0; r < 4; ++r) {
      int m = quad * 4 + r;
      zbuf[m * 132 + nt0 * 16 + l15] = z0[r];
      zbuf[m * 132 + nt1 * 16 + l15] = z1[r];
    }
    *(uint4*)(xbuf + tid * 8) = xcur;
    // BAR2: LDS-only barrier
    asm volatile("s_waitcnt lgkmcnt(0)\ns_barrier" ::: "memory");
    // gates: i,f,g,o = sigmoid; c = f*c + i*g; h = o*sigmoid(c)
    const float* zb = zbuf + pb * 132;
    uint32_t xi = *(const uint32_t*)(xbuf + (0 * 16 + pb) * 32 + pj);
    uint32_t xf = *(const uint32_t*)(xbuf + (1 * 16 + pb) * 32 + pj);
    uint32_t xg = *(const uint32_t*)(xbuf + (2 * 16 + pb) * 32 + pj);
    uint32_t xo = *(const uint32_t*)(xbuf + (3 * 16 + pb) * 32 + pj);
    float i0 = sigf(zb[pj] + bflo(xi)),      i1 = sigf(zb[pj + 1] + bfhi(xi));
    float f0 = sigf(zb[32 + pj] + bflo(xf)), f1 = sigf(zb[32 + pj + 1] + bfhi(xf));
    float g0 = sigf(zb[64 + pj] + bflo(xg)), g1 = sigf(zb[64 + pj + 1] + bfhi(xg));
    float o0 = sigf(zb[96 + pj] + bflo(xo)), o1 = sigf(zb[96 + pj + 1] + bfhi(xo));
    c0 = f0 * c0 + i0 * g0;
    c1 = f1 * c1 + i1 * g1;
    float h0 = o0 * sigf(c0);
    float h1 = o1 * sigf(c1);
    size_t oidx = ((size_t)pb * 1024 + t) * 1024 + dir * 512 + u0 + pj;
    // zero-guard: bump exact-zero bf16 halves to min subnormal (err <= 9e-41)
    uint32_t ha = f2bfbits(h0); ha += (ha == 0u);
    uint32_t hb = f2bfbits(h1); hb += (hb == 0u);
    uint32_t hp = ha | (hb << 16);
    uint32_t* hptr = (uint32_t*)(ynext + oidx);
    if (local) {
      *(volatile uint32_t*)hptr = hp;   // plain store -> local L2 (dirty), fast path
    } else {
      __hip_atomic_store(hptr, hp, __ATOMIC_RELAXED, __HIP_MEMORY_SCOPE_AGENT);
    }
    if (outf) { outf[oidx] = h0; outf[oidx + 1] = h1; }
    asm volatile("" ::: "memory");   // pin store before loop backedge
    xcur = xnxt;
  }
}

// ---------------------------------------------------------------------------
extern "C" void kernel_launch(void* const* d_in, const int* in_sizes, int n_in,
                              void* d_out, int out_size, void* d_ws, size_t ws_size,
                              hipStream_t stream) {
  const float* x  = (const float*)d_in[0];   // [16][1024][1024]
  const float* W  = (const float*)d_in[1];   // [5][2][1024][2048]
  const float* Uh = (const float*)d_in[2];   // [5][2][512][2048]
  const float* b  = (const float*)d_in[3];   // [5][2][2048]

  char* ws = (char*)d_ws;
  size_t off = 0;
  __hip_bfloat16* yA = (__hip_bfloat16*)(ws + off); off += (size_t)16 * 1024 * 1024 * 2;
  __hip_bfloat16* yB = (__hip_bfloat16*)(ws + off); off += (size_t)16 * 1024 * 1024 * 2;
  __hip_bfloat16* xz = (__hip_bfloat16*)(ws + off); off += (size_t)2 * 16 * 1024 * 2048 * 2;
  __hip_bfloat16* Wt = (__hip_bfloat16*)(ws + off); off += (size_t)2 * 2048 * 1024 * 2;
  __hip_bfloat16* Ut = (__hip_bfloat16*)(ws + off); off += (size_t)2 * 2048 * 512 * 2;
  int* claim = (int*)(ws + off); off += 512;   // 80 ints used

  f32_to_bf16_k<<<dim3(16384), dim3(256), 0, stream>>>(x, yA, 4194304);
  hipFuncSetAttribute(reinterpret_cast<const void*>(lstm_rec_k),
                      hipFuncAttributeMaxDynamicSharedMemorySize, 160264);
  for (int l = 0; l < 5; ++l) {
    transpose_bf16_k<<<dim3(16, 32, 2), dim3(256), 0, stream>>>(W + (size_t)l * 2 * 1024 * 2048, Wt, 1024);
    transpose_bf16_k<<<dim3(8, 32, 2),  dim3(256), 0, stream>>>(Uh + (size_t)l * 2 * 512 * 2048, Ut, 512);
    __hip_bfloat16* ycur = (l & 1) ? yB : yA;
    __hip_bfloat16* ynxt = (l & 1) ? yA : yB;
    // zero ynxt (sentinel protocol) + claim zone
    hipMemsetAsync(ynxt, 0, (size_t)16 * 1024 * 1024 * 2, stream);
    hipMemsetAsync(claim, 0, 80 * sizeof(int), stream);
    gemm_xz_k<<<dim3(128, 32), dim3(256), 0, stream>>>(ycur, Wt, b + (size_t)l * 2 * 2048, xz);
    lstm_rec_k<<<dim3(256), dim3(256), 160264, stream>>>(
        Ut, xz, ynxt, (l == 4) ? (float*)d_out : nullptr, claim);
  }
}

// Round 6
// 21423.952 us; speedup vs baseline: 3.8023x; 3.8023x over previous
//
#include <hip/hip_runtime.h>
#include <hip/hip_bf16.h>
#include <stdint.h>

// ---------------------------------------------------------------------------
// Bidirectional 5-layer LSTM (all-sigmoid), B=16, T=1024, D=1024, U=512.
// R8: post-MFMA overhead trim on the proven R3 protocol (poll/store/drain
// barriers identical to R3).
//   - Uh columns permuted per tile: l15 = unit4*4 + gate. All 4 gates of a
//     (batch,unit) live in one wave at lane^1/lane^2 -> c-update via DPP
//     quad-perm butterfly + selects. Deletes zbuf, xbuf, BAR2, and the
//     128-thread divergent gate phase (2 barriers/step, no LDS round trip).
//   - xz stored by the GEMM in MFMA C-fragment order; rec lanes load their
//     own 2x8B fragments directly (no staging).
//   - hbuf pitch 520 -> 528 units: A-frag bank-starts 8 groups x 8 lanes ->
//     16 groups x 4 lanes (halves the ds_read conflict tax).
//   - h stored as packed u32 unit-pairs (pair via one shfl_xor(4)); sentinel
//     stays u32-granular; zero-guard as before.
// ---------------------------------------------------------------------------

typedef __attribute__((ext_vector_type(8))) short short8;
typedef __attribute__((ext_vector_type(4))) float f32x4;

union U128 { uint4 u; short8 s; };
static __device__ __forceinline__ short8 as_short8(uint4 v) { U128 x; x.u = v; return x.s; }

static __device__ __forceinline__ float sigf(float x) { return 1.0f / (1.0f + __expf(-x)); }

static __device__ __forceinline__ uint32_t f2bfbits(float f) {
  union { float f; uint32_t u; } x; x.f = f;
  return (x.u + 0x7fffu + ((x.u >> 16) & 1u)) >> 16;   // RNE; h in (0,1), no NaN
}
static __device__ __forceinline__ float bflo(uint32_t v) {
  union { uint32_t u; float f; } x; x.u = v << 16; return x.f;
}
static __device__ __forceinline__ float bfhi(uint32_t v) {
  union { uint32_t u; float f; } x; x.u = v & 0xffff0000u; return x.f;
}

// ---------------- x (fp32) -> bf16 ----------------
__global__ __launch_bounds__(256) void f32_to_bf16_k(const float* __restrict__ in,
                                                     __hip_bfloat16* __restrict__ out,
                                                     int n4) {
  int i = blockIdx.x * 256 + threadIdx.x;
  if (i < n4) {
    float4 v = ((const float4*)in)[i];
    uint32_t lo = f2bfbits(v.x) | (f2bfbits(v.y) << 16);
    uint32_t hi = f2bfbits(v.z) | (f2bfbits(v.w) << 16);
    ((uint2*)out)[i] = make_uint2(lo, hi);
  }
}

// ---------------- [2][R][2048] fp32 -> [2][2048][R] bf16 transpose ----------------
__global__ __launch_bounds__(256) void transpose_bf16_k(const float* __restrict__ in,
                                                        __hip_bfloat16* __restrict__ outp,
                                                        int R) {
  __shared__ float tile[64][65];
  int d = blockIdx.z;
  int k0 = blockIdx.x * 64;
  int c0 = blockIdx.y * 64;
  const float* inb = in + (size_t)d * R * 2048;
  __hip_bfloat16* ob = outp + (size_t)d * 2048 * R;
  int col = threadIdx.x & 63, rr = threadIdx.x >> 6;
#pragma unroll
  for (int i = 0; i < 16; ++i) {
    int r = rr + i * 4;
    tile[r][col] = inb[(size_t)(k0 + r) * 2048 + c0 + col];
  }
  __syncthreads();
#pragma unroll
  for (int i = 0; i < 16; ++i) {
    int r = rr + i * 4;
    ob[(size_t)(c0 + r) * R + k0 + col] = __float2bfloat16(tile[col][r]);
  }
}

// ---------------- xz GEMM: y[16384,1024] @ Wt[2][2048,1024]^T + b ----------------
// Output layout (per dir,swg,t chunk of 2048 bf16 = 4KB):
//   inner = ((nt*16 + l15)*4 + quad)*4 + r   with  nt = ul>>2 (ul = unit&31),
//   l15 = ((ul&3)<<2)|gate, quad = batch>>2, r = batch&3.
// Matches the rec kernel's MFMA C-fragment (batch = quad*4+r, col = l15).
__global__ __launch_bounds__(256) void gemm_xz_k(const __hip_bfloat16* __restrict__ y,
                                                 const __hip_bfloat16* __restrict__ Wt,
                                                 const float* __restrict__ bias,
                                                 __hip_bfloat16* __restrict__ xz) {
  __shared__ uint4 Asl[8 * 2 * 64];
  __shared__ uint4 Bsl[8 * 2 * 64];
  int m0 = blockIdx.x * 128;
  int dir = blockIdx.y >> 4;
  int n0 = (blockIdx.y & 15) * 128;
  int tid = threadIdx.x, lane = tid & 63, wv = tid >> 6;
  int wm = wv & 1, wn = wv >> 1;
  const __hip_bfloat16* Wd = Wt + (size_t)dir * 2048 * 1024;
  f32x4 acc[4][4] = {};
  for (int kb = 0; kb < 1024; kb += 64) {
    __syncthreads();
#pragma unroll
    for (int i = 0; i < 4; ++i) {
      int slot = i * 256 + tid;
      int ln = slot & 63, kc = (slot >> 6) & 1, mt = slot >> 7;
      int row = mt * 16 + (ln & 15);
      int kk = kc * 32 + (ln >> 4) * 8;
      Asl[slot] = *(const uint4*)(y + (size_t)(m0 + row) * 1024 + kb + kk);
      Bsl[slot] = *(const uint4*)(Wd + (size_t)(n0 + row) * 1024 + kb + kk);
    }
    __syncthreads();
#pragma unroll
    for (int kc = 0; kc < 2; ++kc) {
      short8 af[4], bf[4];
#pragma unroll
      for (int i = 0; i < 4; ++i) {
        af[i] = as_short8(Asl[((wm * 4 + i) * 2 + kc) * 64 + lane]);
        bf[i] = as_short8(Bsl[((wn * 4 + i) * 2 + kc) * 64 + lane]);
      }
#pragma unroll
      for (int i = 0; i < 4; ++i)
#pragma unroll
        for (int j = 0; j < 4; ++j)
          acc[i][j] = __builtin_amdgcn_mfma_f32_16x16x32_bf16(af[i], bf[j], acc[i][j], 0, 0, 0);
    }
  }
  // epilogue: C/D layout col=lane&15, row=(lane>>4)*4+r  [m89-verified]
  int cq = lane >> 4, cn = lane & 15;
#pragma unroll
  for (int i = 0; i < 4; ++i)
#pragma unroll
    for (int j = 0; j < 4; ++j) {
      int n_g = n0 + (wn * 4 + j) * 16 + cn;
      int gate = n_g >> 9, u = n_g & 511, swg = u >> 5, ul = u & 31;
      int nt = ul >> 2, l15 = ((ul & 3) << 2) | gate;
      float bv = bias[dir * 2048 + n_g];
#pragma unroll
      for (int r = 0; r < 4; ++r) {
        int m = m0 + (wm * 4 + i) * 16 + cq * 4 + r;
        int b = m >> 10, t = m & 1023;
        int quad = b >> 2, rr = b & 3;
        size_t addr = (((size_t)(dir * 16 + swg) * 1024 + t) * 2048) +
                      ((nt * 16 + l15) * 4 + quad) * 4 + rr;
        xz[addr] = __float2bfloat16(acc[i][j][r] + bv);
      }
    }
}

// ---------------- persistent bidirectional recurrence ----------------
// 32 blocks: dir = blockIdx&1, slice = blockIdx>>1 (16 slices/dir, 32 u-cols).
// LDS: uh 128KB | hbuf 16x528 bf16 = 16896B -> 147968 B total.
// Sentinel exchange: ynext pre-zeroed; h words never zero (guarded); readers
// poll the t-indexed data words directly until all nonzero. (R3 protocol.)
__global__ __launch_bounds__(256) void lstm_rec_k(const __hip_bfloat16* __restrict__ Ut,  // [2][2048][512]
                                                  const __hip_bfloat16* __restrict__ xz,  // [dir][swg][t][2048]
                                                  __hip_bfloat16* __restrict__ ynext,     // [16][1024][1024], pre-zeroed
                                                  float* __restrict__ outf) {             // last layer or null
  extern __shared__ char smem[];
  uint4* uh = (uint4*)smem;                                 // 8192 x 16B
  __hip_bfloat16* hbuf = (__hip_bfloat16*)(smem + 131072);  // [16][528]
  int dir = blockIdx.x & 1;
  int swg = blockIdx.x >> 1;
  int u0 = swg * 32;
  int tid = threadIdx.x, lane = tid & 63, wv = tid >> 6;
  int quad = lane >> 4, l15 = lane & 15;
  const __hip_bfloat16* Ud = Ut + (size_t)dir * 2048 * 512;

  // fill LDS with Uh slice, pre-fragmented, gate-interleaved columns:
  // tile nt col l15 -> unit u0 + nt*4 + (l15>>2), gate = l15&3.
#pragma unroll 4
  for (int i = 0; i < 32; ++i) {
    int slot = i * 256 + tid;
    int ls = slot & 63, kc = (slot >> 6) & 15, nt = slot >> 10;
    int n_g = (ls & 3) * 512 + u0 + nt * 4 + ((ls & 15) >> 2);
    int k = kc * 32 + (ls >> 4) * 8;
    uh[slot] = *(const uint4*)(Ud + (size_t)n_g * 512 + k);
  }
  __syncthreads();

  int nt0 = wv * 2, nt1 = wv * 2 + 1;
  // per-lane xz fragment offsets (elements) within a (dir,swg,t) chunk
  int o0 = ((nt0 * 16 + l15) * 4 + quad) * 4;
  int o1 = ((nt1 * 16 + l15) * 4 + quad) * 4;
  // gate-id predicates (lane&3 == gate), unit4 = l15>>2
  bool gb0 = (lane & 1) != 0, gb1 = (lane & 2) != 0;
  int u4 = l15 >> 2;
  int unit = u0 + wv * 8 + 0 /*nt local later*/;
  bool st_act = ((l15 & 7) == 0);   // gate==0 && even u4: the pair-store lane
  float cst0[4] = {0.f, 0.f, 0.f, 0.f};   // c-state tile nt0 (replicated x4 lanes)
  float cst1[4] = {0.f, 0.f, 0.f, 0.f};   // c-state tile nt1

  int t0 = dir ? 1023 : 0;
  const __hip_bfloat16* xc0 = xz + ((size_t)(dir * 16 + swg) * 1024 + t0) * 2048;
  uint2 xq0 = *(const uint2*)(xc0 + o0);
  uint2 xq1 = *(const uint2*)(xc0 + o1);

  for (int s = 0; s < 1024; ++s) {
    int t = dir ? (1023 - s) : s;
    // prefetch next step's xz fragments (overlaps the poll)
    uint2 xn0 = xq0, xn1 = xq1;
    if (s < 1023) {
      int tn = dir ? (1022 - s) : (s + 1);
      const __hip_bfloat16* xc = xz + ((size_t)(dir * 16 + swg) * 1024 + tn) * 2048;
      xn0 = *(const uint2*)(xc + o0);
      xn1 = *(const uint2*)(xc + o1);
    }
    f32x4 z0 = {}, z1 = {};
    if (s > 0) {
      int tprev = dir ? (t + 1) : (t - 1);
      // sentinel poll == coalesced h load: 64B/thread, retry words still zero.
      unsigned long long hv[8];
      const unsigned long long* gp[8];
#pragma unroll
      for (int i = 0; i < 4; ++i) {
        int v = i * 2048 + tid * 8;
        int b = v >> 9, col = v & 511;
        const unsigned long long* g =
            (const unsigned long long*)(ynext + ((size_t)b * 1024 + tprev) * 1024 + dir * 512 + col);
        gp[2 * i] = g;
        gp[2 * i + 1] = g + 1;
      }
#pragma unroll
      for (int i = 0; i < 8; ++i)
        hv[i] = __hip_atomic_load(gp[i], __ATOMIC_RELAXED, __HIP_MEMORY_SCOPE_AGENT);
      for (;;) {
        bool ok = true;
#pragma unroll
        for (int i = 0; i < 8; ++i)
          ok &= ((uint32_t)hv[i] != 0u) && ((uint32_t)(hv[i] >> 32) != 0u);
        if (ok) break;
#pragma unroll
        for (int i = 0; i < 8; ++i)
          if (((uint32_t)hv[i] == 0u) || ((uint32_t)(hv[i] >> 32) == 0u))
            hv[i] = __hip_atomic_load(gp[i], __ATOMIC_RELAXED, __HIP_MEMORY_SCOPE_AGENT);
      }
#pragma unroll
      for (int i = 0; i < 4; ++i) {
        int v = i * 2048 + tid * 8;
        int b = v >> 9, col = v & 511;
        unsigned long long* lp = (unsigned long long*)(hbuf + b * 528 + col);
        lp[0] = hv[2 * i];
        lp[1] = hv[2 * i + 1];
      }
      __syncthreads();   // BAR1
      // A-frags from LDS (b128, pitch 528: 16 bank-starts x 4 lanes) + MFMA
#pragma unroll
      for (int kc = 0; kc < 16; ++kc) {
        short8 afrag = *(const short8*)(hbuf + l15 * 528 + kc * 32 + quad * 8);
        z0 = __builtin_amdgcn_mfma_f32_16x16x32_bf16(afrag, as_short8(uh[(nt0 * 16 + kc) * 64 + lane]), z0, 0, 0, 0);
        z1 = __builtin_amdgcn_mfma_f32_16x16x32_bf16(afrag, as_short8(uh[(nt1 * 16 + kc) * 64 + lane]), z1, 0, 0, 0);
      }
    }
    // ---- gates in-wave via quad-perm butterfly; no barrier, no LDS ----
    float xr0[4] = {bflo(xq0.x), bfhi(xq0.x), bflo(xq0.y), bfhi(xq0.y)};
    float xr1[4] = {bflo(xq1.x), bfhi(xq1.x), bflo(xq1.y), bfhi(xq1.y)};
#pragma unroll
    for (int tl = 0; tl < 2; ++tl) {
      int unit_e = u0 + wv * 8 + (tl ? nt1 & 1 ? 0 : 0 : 0);  // computed below properly
#pragma unroll
      for (int r = 0; r < 4; ++r) {
        float zz = tl ? z1[r] : z0[r];
        float xx = tl ? xr1[r] : xr0[r];
        float sv = sigf(zz + xx);
        float b1 = __shfl_xor(sv, 1);
        float b2 = __shfl_xor(sv, 2);
        float b3 = __shfl_xor(b1, 2);
        // per-gate role mapping (verified): ig, f, o
        float ig = gb0 ? (b1 * b3) : (sv * b2);
        float fg = gb0 ? (gb1 ? b2 : sv) : (gb1 ? b3 : b1);
        float og = gb0 ? (gb1 ? sv : b2) : (gb1 ? b1 : b3);
        float& c = tl ? cst1[r] : cst0[r];
        c = fg * c + ig;
        float h = og * sigf(c);
        // pack unit-pair: partner lane = lane^4 (u4^1, same gate)
        uint32_t hb = f2bfbits(h);
        hb += (hb == 0u);                       // zero-guard (<= 9e-41 err)
        uint32_t hpart = __shfl_xor(hb, 4);
        uint32_t hfull = __float_as_uint(h);
        uint32_t hfpart = __shfl_xor(hfull, 4);
        if (st_act) {
          int un = u0 + wv * 8 + (tl ? 4 : 0) + u4;   // nt local: tl*4 + u4 (u4 even)
          int batch = quad * 4 + r;
          size_t oidx = ((size_t)batch * 1024 + t) * 1024 + dir * 512 + un;
          __hip_atomic_store((uint32_t*)(ynext + oidx), hb | (hpart << 16),
                             __ATOMIC_RELAXED, __HIP_MEMORY_SCOPE_AGENT);
          if (outf) *(uint2*)(outf + oidx) = make_uint2(hfull, hfpart);
        }
      }
    }
    __syncthreads();   // drains vmcnt: h stores visible before next poll (R3-proven)
    xq0 = xn0;
    xq1 = xn1;
  }
  (void)unit;
}

// ---------------------------------------------------------------------------
extern "C" void kernel_launch(void* const* d_in, const int* in_sizes, int n_in,
                              void* d_out, int out_size, void* d_ws, size_t ws_size,
                              hipStream_t stream) {
  const float* x  = (const float*)d_in[0];   // [16][1024][1024]
  const float* W  = (const float*)d_in[1];   // [5][2][1024][2048]
  const float* Uh = (const float*)d_in[2];   // [5][2][512][2048]
  const float* b  = (const float*)d_in[3];   // [5][2][2048]

  char* ws = (char*)d_ws;
  size_t off = 0;
  __hip_bfloat16* yA = (__hip_bfloat16*)(ws + off); off += (size_t)16 * 1024 * 1024 * 2;
  __hip_bfloat16* yB = (__hip_bfloat16*)(ws + off); off += (size_t)16 * 1024 * 1024 * 2;
  __hip_bfloat16* xz = (__hip_bfloat16*)(ws + off); off += (size_t)2 * 16 * 1024 * 2048 * 2;
  __hip_bfloat16* Wt = (__hip_bfloat16*)(ws + off); off += (size_t)2 * 2048 * 1024 * 2;
  __hip_bfloat16* Ut = (__hip_bfloat16*)(ws + off); off += (size_t)2 * 2048 * 512 * 2;

  f32_to_bf16_k<<<dim3(16384), dim3(256), 0, stream>>>(x, yA, 4194304);
  hipFuncSetAttribute(reinterpret_cast<const void*>(lstm_rec_k),
                      hipFuncAttributeMaxDynamicSharedMemorySize, 147968);
  for (int l = 0; l < 5; ++l) {
    transpose_bf16_k<<<dim3(16, 32, 2), dim3(256), 0, stream>>>(W + (size_t)l * 2 * 1024 * 2048, Wt, 1024);
    transpose_bf16_k<<<dim3(8, 32, 2),  dim3(256), 0, stream>>>(Uh + (size_t)l * 2 * 512 * 2048, Ut, 512);
    __hip_bfloat16* ycur = (l & 1) ? yB : yA;
    __hip_bfloat16* ynxt = (l & 1) ? yA : yB;
    // zero ynxt: sentinel protocol requires unwritten h words to read as 0.
    hipMemsetAsync(ynxt, 0, (size_t)16 * 1024 * 1024 * 2, stream);
    gemm_xz_k<<<dim3(128, 32), dim3(256), 0, stream>>>(ycur, Wt, b + (size_t)l * 2 * 2048, xz);
    lstm_rec_k<<<dim3(32), dim3(256), 147968, stream>>>(
        Ut, xz, ynxt, (l == 4) ? (float*)d_out : nullptr);
  }
}

// Round 7
// 15561.188 us; speedup vs baseline: 5.2348x; 1.3768x over previous
//
#include <hip/hip_runtime.h>
#include <hip/hip_bf16.h>
#include <stdint.h>

// ---------------------------------------------------------------------------
// Bidirectional 5-layer LSTM (all-sigmoid), B=16, T=1024, D=1024, U=512.
// R9 = R3 + two surgical changes:
//   1. EARLY POLL ISSUE: the 8 sentinel poll loads for step s+1 (addresses =
//      h at time t_s, known at step-s tail) are issued right after the
//      h-store, BEFORE the drain barrier. __syncthreads drains stores and
//      polls concurrently (barrier cost ~= max of the two RTs, not sum), so
//      the head-of-step check usually passes with no detect round trip.
//      Late blocks always pass first try -> jitter self-correction.
//      Sentinel retry (recomputed addresses) covers first-try misses.
//   2. hbuf pitch 520 -> 528 units: A-frag ds_read_b128 bank conflict
//      8-way -> 4-way (mechanism measured in R8: 1.47e7 -> 4.2e6).
// Everything else (protocol, store pattern, barriers, gates) is exactly R3.
// ---------------------------------------------------------------------------

typedef __attribute__((ext_vector_type(8))) short short8;
typedef __attribute__((ext_vector_type(4))) float f32x4;

union U128 { uint4 u; short8 s; };
static __device__ __forceinline__ short8 as_short8(uint4 v) { U128 x; x.u = v; return x.s; }

static __device__ __forceinline__ float sigf(float x) { return 1.0f / (1.0f + __expf(-x)); }

static __device__ __forceinline__ uint32_t f2bfbits(float f) {
  union { float f; uint32_t u; } x; x.f = f;
  return (x.u + 0x7fffu + ((x.u >> 16) & 1u)) >> 16;   // RNE; h in (0,1), no NaN
}
static __device__ __forceinline__ float bflo(uint32_t v) {
  union { uint32_t u; float f; } x; x.u = v << 16; return x.f;
}
static __device__ __forceinline__ float bfhi(uint32_t v) {
  union { uint32_t u; float f; } x; x.u = v & 0xffff0000u; return x.f;
}

// ---------------- x (fp32) -> bf16 ----------------
__global__ __launch_bounds__(256) void f32_to_bf16_k(const float* __restrict__ in,
                                                     __hip_bfloat16* __restrict__ out,
                                                     int n4) {
  int i = blockIdx.x * 256 + threadIdx.x;
  if (i < n4) {
    float4 v = ((const float4*)in)[i];
    uint32_t lo = f2bfbits(v.x) | (f2bfbits(v.y) << 16);
    uint32_t hi = f2bfbits(v.z) | (f2bfbits(v.w) << 16);
    ((uint2*)out)[i] = make_uint2(lo, hi);
  }
}

// ---------------- [2][R][2048] fp32 -> [2][2048][R] bf16 transpose ----------------
__global__ __launch_bounds__(256) void transpose_bf16_k(const float* __restrict__ in,
                                                        __hip_bfloat16* __restrict__ outp,
                                                        int R) {
  __shared__ float tile[64][65];
  int d = blockIdx.z;
  int k0 = blockIdx.x * 64;
  int c0 = blockIdx.y * 64;
  const float* inb = in + (size_t)d * R * 2048;
  __hip_bfloat16* ob = outp + (size_t)d * 2048 * R;
  int col = threadIdx.x & 63, rr = threadIdx.x >> 6;
#pragma unroll
  for (int i = 0; i < 16; ++i) {
    int r = rr + i * 4;
    tile[r][col] = inb[(size_t)(k0 + r) * 2048 + c0 + col];
  }
  __syncthreads();
#pragma unroll
  for (int i = 0; i < 16; ++i) {
    int r = rr + i * 4;
    ob[(size_t)(c0 + r) * R + k0 + col] = __float2bfloat16(tile[col][r]);
  }
}

// ---------------- xz GEMM: y[16384,1024] @ Wt[2][2048,1024]^T + b ----------------
// Output layout: xz[dir][swg(16)][t(1024)][q(4)][b(16)][j(32)]  (4KB per (dir,swg,t))
__global__ __launch_bounds__(256) void gemm_xz_k(const __hip_bfloat16* __restrict__ y,
                                                 const __hip_bfloat16* __restrict__ Wt,
                                                 const float* __restrict__ bias,
                                                 __hip_bfloat16* __restrict__ xz) {
  __shared__ uint4 Asl[8 * 2 * 64];
  __shared__ uint4 Bsl[8 * 2 * 64];
  int m0 = blockIdx.x * 128;
  int dir = blockIdx.y >> 4;
  int n0 = (blockIdx.y & 15) * 128;
  int tid = threadIdx.x, lane = tid & 63, wv = tid >> 6;
  int wm = wv & 1, wn = wv >> 1;
  const __hip_bfloat16* Wd = Wt + (size_t)dir * 2048 * 1024;
  f32x4 acc[4][4] = {};
  for (int kb = 0; kb < 1024; kb += 64) {
    __syncthreads();
#pragma unroll
    for (int i = 0; i < 4; ++i) {
      int slot = i * 256 + tid;
      int ln = slot & 63, kc = (slot >> 6) & 1, mt = slot >> 7;
      int row = mt * 16 + (ln & 15);
      int kk = kc * 32 + (ln >> 4) * 8;
      Asl[slot] = *(const uint4*)(y + (size_t)(m0 + row) * 1024 + kb + kk);
      Bsl[slot] = *(const uint4*)(Wd + (size_t)(n0 + row) * 1024 + kb + kk);
    }
    __syncthreads();
#pragma unroll
    for (int kc = 0; kc < 2; ++kc) {
      short8 af[4], bf[4];
#pragma unroll
      for (int i = 0; i < 4; ++i) {
        af[i] = as_short8(Asl[((wm * 4 + i) * 2 + kc) * 64 + lane]);
        bf[i] = as_short8(Bsl[((wn * 4 + i) * 2 + kc) * 64 + lane]);
      }
#pragma unroll
      for (int i = 0; i < 4; ++i)
#pragma unroll
        for (int j = 0; j < 4; ++j)
          acc[i][j] = __builtin_amdgcn_mfma_f32_16x16x32_bf16(af[i], bf[j], acc[i][j], 0, 0, 0);
    }
  }
  // epilogue: C/D layout col=lane&15, row=(lane>>4)*4+r  [m89-verified]
  int cq = lane >> 4, cn = lane & 15;
#pragma unroll
  for (int i = 0; i < 4; ++i)
#pragma unroll
    for (int j = 0; j < 4; ++j) {
      int n_g = n0 + (wn * 4 + j) * 16 + cn;
      int q = n_g >> 9, u = n_g & 511, swg = u >> 5, jj = u & 31;
      float bv = bias[dir * 2048 + n_g];
#pragma unroll
      for (int r = 0; r < 4; ++r) {
        int m = m0 + (wm * 4 + i) * 16 + cq * 4 + r;
        int b = m >> 10, t = m & 1023;
        size_t addr = (((size_t)(dir * 16 + swg) * 1024 + t) * 2048) + (q * 16 + b) * 32 + jj;
        xz[addr] = __float2bfloat16(acc[i][j][r] + bv);
      }
    }
}

// ---------------- persistent bidirectional recurrence ----------------
// 32 blocks: dir = blockIdx&1, slice = blockIdx>>1 (16 slices/dir, 32 u-cols).
// LDS: uh 128KB | hbuf 16x528 bf16 = 16896B | zbuf 16x132 f32 = 8448B |
//      xbuf 2048 bf16 = 4KB  -> 160512 B total.
// Sentinel exchange: ynext pre-zeroed; h words never zero (guarded); readers
// poll the t-indexed data words until all nonzero (R3 protocol); poll ISSUE
// happens at the previous step's tail (overlapped with the store drain).
__global__ __launch_bounds__(256) void lstm_rec_k(const __hip_bfloat16* __restrict__ Ut,  // [2][2048][512]
                                                  const __hip_bfloat16* __restrict__ xz,  // [dir][swg][t][2048]
                                                  __hip_bfloat16* __restrict__ ynext,     // [16][1024][1024], pre-zeroed
                                                  float* __restrict__ outf) {             // last layer or null
  extern __shared__ char smem[];
  uint4* uh = (uint4*)smem;                                 // 8192 x 16B
  __hip_bfloat16* hbuf = (__hip_bfloat16*)(smem + 131072);  // [16][528]
  float* zbuf = (float*)(smem + 147968);                    // [16][132]
  __hip_bfloat16* xbuf = (__hip_bfloat16*)(smem + 156416);  // [2048]
  int dir = blockIdx.x & 1;
  int swg = blockIdx.x >> 1;
  int u0 = swg * 32;
  int tid = threadIdx.x, lane = tid & 63, wv = tid >> 6;
  int quad = lane >> 4, l15 = lane & 15;
  const __hip_bfloat16* Ud = Ut + (size_t)dir * 2048 * 512;

  // fill LDS with Uh slice, pre-fragmented (same as R3)
#pragma unroll 4
  for (int i = 0; i < 32; ++i) {
    int slot = i * 256 + tid;
    int ls = slot & 63, kc = (slot >> 6) & 15, nt = slot >> 10;
    int n_g = (nt >> 1) * 512 + u0 + (nt & 1) * 16 + (ls & 15);
    int k = kc * 32 + (ls >> 4) * 8;
    uh[slot] = *(const uint4*)(Ud + (size_t)n_g * 512 + k);
  }
  __syncthreads();

  int nt0 = wv * 2, nt1 = wv * 2 + 1;
  int pb = tid >> 4, pj = (tid & 15) * 2;
  float c0 = 0.f, c1 = 0.f;

  int t0 = dir ? 1023 : 0;
  const uint4* xp0 = (const uint4*)(xz + ((size_t)(dir * 16 + swg) * 1024 + t0) * 2048) + tid;
  uint4 xcur = *xp0;

  unsigned long long hv[8];   // early-issued poll values, live across BAR3

  for (int s = 0; s < 1024; ++s) {
    int t = dir ? (1023 - s) : s;
    // prefetch next step's xz (overlaps the head phase)
    uint4 xnxt;
    if (s < 1023) {
      int tn = dir ? (1022 - s) : (s + 1);
      xnxt = *((const uint4*)(xz + ((size_t)(dir * 16 + swg) * 1024 + tn) * 2048) + tid);
    }
    f32x4 z0 = {}, z1 = {};
    if (s > 0) {
      int tprev = dir ? (t + 1) : (t - 1);
      // hv[] were issued at the previous step's tail and drained by BAR3:
      // values are ready NOW. Retry only still-zero words (addresses recomputed).
      const unsigned long long* gp[8];
#pragma unroll
      for (int i = 0; i < 4; ++i) {
        int v = i * 2048 + tid * 8;
        int b = v >> 9, col = v & 511;
        const unsigned long long* g =
            (const unsigned long long*)(ynext + ((size_t)b * 1024 + tprev) * 1024 + dir * 512 + col);
        gp[2 * i] = g;
        gp[2 * i + 1] = g + 1;
      }
      for (;;) {
        bool ok = true;
#pragma unroll
        for (int i = 0; i < 8; ++i)
          ok &= ((uint32_t)hv[i] != 0u) && ((uint32_t)(hv[i] >> 32) != 0u);
        if (ok) break;
#pragma unroll
        for (int i = 0; i < 8; ++i)
          if (((uint32_t)hv[i] == 0u) || ((uint32_t)(hv[i] >> 32) == 0u))
            hv[i] = __hip_atomic_load(gp[i], __ATOMIC_RELAXED, __HIP_MEMORY_SCOPE_AGENT);
      }
#pragma unroll
      for (int i = 0; i < 4; ++i) {
        int v = i * 2048 + tid * 8;
        int b = v >> 9, col = v & 511;
        unsigned long long* lp = (unsigned long long*)(hbuf + b * 528 + col);
        lp[0] = hv[2 * i];
        lp[1] = hv[2 * i + 1];
      }
      __syncthreads();   // BAR1
      // A-frags from LDS (b128, pitch 528: 16 bank-starts x 4 lanes) + MFMA
#pragma unroll
      for (int kc = 0; kc < 16; ++kc) {
        short8 afrag = *(const short8*)(hbuf + l15 * 528 + kc * 32 + quad * 8);
        z0 = __builtin_amdgcn_mfma_f32_16x16x32_bf16(afrag, as_short8(uh[(nt0 * 16 + kc) * 64 + lane]), z0, 0, 0, 0);
        z1 = __builtin_amdgcn_mfma_f32_16x16x32_bf16(afrag, as_short8(uh[(nt1 * 16 + kc) * 64 + lane]), z1, 0, 0, 0);
      }
    }
    // publish z to zbuf (pitch 132); stage xz chunk to xbuf
#pragma unroll
    for (int r = 0; r < 4; ++r) {
      int m = quad * 4 + r;
      zbuf[m * 132 + nt0 * 16 + l15] = z0[r];
      zbuf[m * 132 + nt1 * 16 + l15] = z1[r];
    }
    *(uint4*)(xbuf + tid * 8) = xcur;
    __syncthreads();   // BAR2
    // gates: i,f,g,o = sigmoid; c = f*c + i*g; h = o*sigmoid(c)
    const float* zb = zbuf + pb * 132;
    uint32_t xi = *(const uint32_t*)(xbuf + (0 * 16 + pb) * 32 + pj);
    uint32_t xf = *(const uint32_t*)(xbuf + (1 * 16 + pb) * 32 + pj);
    uint32_t xg = *(const uint32_t*)(xbuf + (2 * 16 + pb) * 32 + pj);
    uint32_t xo = *(const uint32_t*)(xbuf + (3 * 16 + pb) * 32 + pj);
    float i0 = sigf(zb[pj] + bflo(xi)),      i1 = sigf(zb[pj + 1] + bfhi(xi));
    float f0 = sigf(zb[32 + pj] + bflo(xf)), f1 = sigf(zb[32 + pj + 1] + bfhi(xf));
    float g0 = sigf(zb[64 + pj] + bflo(xg)), g1 = sigf(zb[64 + pj + 1] + bfhi(xg));
    float o0 = sigf(zb[96 + pj] + bflo(xo)), o1 = sigf(zb[96 + pj + 1] + bfhi(xo));
    c0 = f0 * c0 + i0 * g0;
    c1 = f1 * c1 + i1 * g1;
    float h0 = o0 * sigf(c0);
    float h1 = o1 * sigf(c1);
    size_t oidx = ((size_t)pb * 1024 + t) * 1024 + dir * 512 + u0 + pj;
    // pack with zero-guard: bump exact-zero bf16 halves to the min subnormal
    // (error <= 9e-41) so a packed word can never be 0 -> sentinel-safe.
    uint32_t ha = f2bfbits(h0); ha += (ha == 0u);
    uint32_t hb = f2bfbits(h1); hb += (hb == 0u);
    uint32_t hp = ha | (hb << 16);
    __hip_atomic_store((uint32_t*)(ynext + oidx), hp, __ATOMIC_RELAXED, __HIP_MEMORY_SCOPE_AGENT);
    if (outf) { outf[oidx] = h0; outf[oidx + 1] = h1; }
    // EARLY POLL ISSUE for step s+1: target h at time t (just stored by all
    // blocks). Issued before the drain so load-RT overlaps store-ack; any
    // word still zero at the head check gets retried there (sentinel-safe:
    // addresses are write-once per layer, nonzero => final value).
    if (s < 1023) {
#pragma unroll
      for (int i = 0; i < 4; ++i) {
        int v = i * 2048 + tid * 8;
        int b = v >> 9, col = v & 511;
        const unsigned long long* g =
            (const unsigned long long*)(ynext + ((size_t)b * 1024 + t) * 1024 + dir * 512 + col);
        hv[2 * i]     = __hip_atomic_load(g,     __ATOMIC_RELAXED, __HIP_MEMORY_SCOPE_AGENT);
        hv[2 * i + 1] = __hip_atomic_load(g + 1, __ATOMIC_RELAXED, __HIP_MEMORY_SCOPE_AGENT);
      }
    }
    __syncthreads();   // BAR3: drains h stores AND early polls concurrently
    xcur = xnxt;
  }
}

// ---------------------------------------------------------------------------
extern "C" void kernel_launch(void* const* d_in, const int* in_sizes, int n_in,
                              void* d_out, int out_size, void* d_ws, size_t ws_size,
                              hipStream_t stream) {
  const float* x  = (const float*)d_in[0];   // [16][1024][1024]
  const float* W  = (const float*)d_in[1];   // [5][2][1024][2048]
  const float* Uh = (const float*)d_in[2];   // [5][2][512][2048]
  const float* b  = (const float*)d_in[3];   // [5][2][2048]

  char* ws = (char*)d_ws;
  size_t off = 0;
  __hip_bfloat16* yA = (__hip_bfloat16*)(ws + off); off += (size_t)16 * 1024 * 1024 * 2;
  __hip_bfloat16* yB = (__hip_bfloat16*)(ws + off); off += (size_t)16 * 1024 * 1024 * 2;
  __hip_bfloat16* xz = (__hip_bfloat16*)(ws + off); off += (size_t)2 * 16 * 1024 * 2048 * 2;
  __hip_bfloat16* Wt = (__hip_bfloat16*)(ws + off); off += (size_t)2 * 2048 * 1024 * 2;
  __hip_bfloat16* Ut = (__hip_bfloat16*)(ws + off); off += (size_t)2 * 2048 * 512 * 2;

  f32_to_bf16_k<<<dim3(16384), dim3(256), 0, stream>>>(x, yA, 4194304);
  hipFuncSetAttribute(reinterpret_cast<const void*>(lstm_rec_k),
                      hipFuncAttributeMaxDynamicSharedMemorySize, 160512);
  for (int l = 0; l < 5; ++l) {
    transpose_bf16_k<<<dim3(16, 32, 2), dim3(256), 0, stream>>>(W + (size_t)l * 2 * 1024 * 2048, Wt, 1024);
    transpose_bf16_k<<<dim3(8, 32, 2),  dim3(256), 0, stream>>>(Uh + (size_t)l * 2 * 512 * 2048, Ut, 512);
    __hip_bfloat16* ycur = (l & 1) ? yB : yA;
    __hip_bfloat16* ynxt = (l & 1) ? yA : yB;
    // zero ynxt: sentinel protocol requires unwritten h words to read as 0.
    hipMemsetAsync(ynxt, 0, (size_t)16 * 1024 * 1024 * 2, stream);
    gemm_xz_k<<<dim3(128, 32), dim3(256), 0, stream>>>(ycur, Wt, b + (size_t)l * 2 * 2048, xz);
    lstm_rec_k<<<dim3(32), dim3(256), 160512, stream>>>(
        Ut, xz, ynxt, (l == 4) ? (float*)d_out : nullptr);
  }
}

// Round 8
// 14818.008 us; speedup vs baseline: 5.4974x; 1.0502x over previous
//
#include <hip/hip_runtime.h>
#include <hip/hip_bf16.h>
#include <stdint.h>

// ---------------------------------------------------------------------------
// Bidirectional 5-layer LSTM (all-sigmoid), B=16, T=1024, D=1024, U=512.
// R10 = R3 (the champion) + the ONLY twice-confirmed mechanism from R8/R9:
//   - hbuf pitch 520 -> 528 units (1056B = 32 mod 128): A-frag ds_read_b128
//     bank-starts go from 8 groups x 8 lanes to 16 groups x 4 lanes.
//     Measured: SQ_LDS_BANK_CONFLICT 1.47e7 -> 4.2-6.3e6 (R8, R9).
//   - zbuf pitch 128 -> 132 f32: publish conflict 4-way -> <=2-way.
// Everything else is byte-identical to R3. In particular the exchange
// discipline (store -> __syncthreads vmcnt(0) drain -> THEN poll) is kept:
// R5/R9 proved (WRITE_SIZE 3x + regression) that polls racing in-flight
// stores thrash the LLC. Serialize-then-poll IS the fast path.
// ---------------------------------------------------------------------------

typedef __attribute__((ext_vector_type(8))) short short8;
typedef __attribute__((ext_vector_type(4))) float f32x4;

union U128 { uint4 u; short8 s; };
static __device__ __forceinline__ short8 as_short8(uint4 v) { U128 x; x.u = v; return x.s; }

static __device__ __forceinline__ float sigf(float x) { return 1.0f / (1.0f + __expf(-x)); }

static __device__ __forceinline__ uint32_t f2bfbits(float f) {
  union { float f; uint32_t u; } x; x.f = f;
  return (x.u + 0x7fffu + ((x.u >> 16) & 1u)) >> 16;   // RNE; h in (0,1), no NaN
}
static __device__ __forceinline__ float bflo(uint32_t v) {
  union { uint32_t u; float f; } x; x.u = v << 16; return x.f;
}
static __device__ __forceinline__ float bfhi(uint32_t v) {
  union { uint32_t u; float f; } x; x.u = v & 0xffff0000u; return x.f;
}

// ---------------- x (fp32) -> bf16 ----------------
__global__ __launch_bounds__(256) void f32_to_bf16_k(const float* __restrict__ in,
                                                     __hip_bfloat16* __restrict__ out,
                                                     int n4) {
  int i = blockIdx.x * 256 + threadIdx.x;
  if (i < n4) {
    float4 v = ((const float4*)in)[i];
    uint32_t lo = f2bfbits(v.x) | (f2bfbits(v.y) << 16);
    uint32_t hi = f2bfbits(v.z) | (f2bfbits(v.w) << 16);
    ((uint2*)out)[i] = make_uint2(lo, hi);
  }
}

// ---------------- [2][R][2048] fp32 -> [2][2048][R] bf16 transpose ----------------
__global__ __launch_bounds__(256) void transpose_bf16_k(const float* __restrict__ in,
                                                        __hip_bfloat16* __restrict__ outp,
                                                        int R) {
  __shared__ float tile[64][65];
  int d = blockIdx.z;
  int k0 = blockIdx.x * 64;
  int c0 = blockIdx.y * 64;
  const float* inb = in + (size_t)d * R * 2048;
  __hip_bfloat16* ob = outp + (size_t)d * 2048 * R;
  int col = threadIdx.x & 63, rr = threadIdx.x >> 6;
#pragma unroll
  for (int i = 0; i < 16; ++i) {
    int r = rr + i * 4;
    tile[r][col] = inb[(size_t)(k0 + r) * 2048 + c0 + col];
  }
  __syncthreads();
#pragma unroll
  for (int i = 0; i < 16; ++i) {
    int r = rr + i * 4;
    ob[(size_t)(c0 + r) * R + k0 + col] = __float2bfloat16(tile[col][r]);
  }
}

// ---------------- xz GEMM: y[16384,1024] @ Wt[2][2048,1024]^T + b ----------------
// Output layout: xz[dir][swg(16)][t(1024)][q(4)][b(16)][j(32)]  (4KB per (dir,swg,t))
__global__ __launch_bounds__(256) void gemm_xz_k(const __hip_bfloat16* __restrict__ y,
                                                 const __hip_bfloat16* __restrict__ Wt,
                                                 const float* __restrict__ bias,
                                                 __hip_bfloat16* __restrict__ xz) {
  __shared__ uint4 Asl[8 * 2 * 64];
  __shared__ uint4 Bsl[8 * 2 * 64];
  int m0 = blockIdx.x * 128;
  int dir = blockIdx.y >> 4;
  int n0 = (blockIdx.y & 15) * 128;
  int tid = threadIdx.x, lane = tid & 63, wv = tid >> 6;
  int wm = wv & 1, wn = wv >> 1;
  const __hip_bfloat16* Wd = Wt + (size_t)dir * 2048 * 1024;
  f32x4 acc[4][4] = {};
  for (int kb = 0; kb < 1024; kb += 64) {
    __syncthreads();
#pragma unroll
    for (int i = 0; i < 4; ++i) {
      int slot = i * 256 + tid;
      int ln = slot & 63, kc = (slot >> 6) & 1, mt = slot >> 7;
      int row = mt * 16 + (ln & 15);
      int kk = kc * 32 + (ln >> 4) * 8;
      Asl[slot] = *(const uint4*)(y + (size_t)(m0 + row) * 1024 + kb + kk);
      Bsl[slot] = *(const uint4*)(Wd + (size_t)(n0 + row) * 1024 + kb + kk);
    }
    __syncthreads();
#pragma unroll
    for (int kc = 0; kc < 2; ++kc) {
      short8 af[4], bf[4];
#pragma unroll
      for (int i = 0; i < 4; ++i) {
        af[i] = as_short8(Asl[((wm * 4 + i) * 2 + kc) * 64 + lane]);
        bf[i] = as_short8(Bsl[((wn * 4 + i) * 2 + kc) * 64 + lane]);
      }
#pragma unroll
      for (int i = 0; i < 4; ++i)
#pragma unroll
        for (int j = 0; j < 4; ++j)
          acc[i][j] = __builtin_amdgcn_mfma_f32_16x16x32_bf16(af[i], bf[j], acc[i][j], 0, 0, 0);
    }
  }
  // epilogue: C/D layout col=lane&15, row=(lane>>4)*4+r  [m89-verified]
  int cq = lane >> 4, cn = lane & 15;
#pragma unroll
  for (int i = 0; i < 4; ++i)
#pragma unroll
    for (int j = 0; j < 4; ++j) {
      int n_g = n0 + (wn * 4 + j) * 16 + cn;
      int q = n_g >> 9, u = n_g & 511, swg = u >> 5, jj = u & 31;
      float bv = bias[dir * 2048 + n_g];
#pragma unroll
      for (int r = 0; r < 4; ++r) {
        int m = m0 + (wm * 4 + i) * 16 + cq * 4 + r;
        int b = m >> 10, t = m & 1023;
        size_t addr = (((size_t)(dir * 16 + swg) * 1024 + t) * 2048) + (q * 16 + b) * 32 + jj;
        xz[addr] = __float2bfloat16(acc[i][j][r] + bv);
      }
    }
}

// ---------------- persistent bidirectional recurrence ----------------
// 32 blocks: dir = blockIdx&1, slice = blockIdx>>1 (16 slices/dir, 32 u-cols).
// LDS: uh 128KB | hbuf 16x528 bf16 = 16896B | zbuf 16x132 f32 = 8448B |
//      xbuf 2048 bf16 = 4KB  -> 160512 B total.
// Sentinel exchange: ynext pre-zeroed; h words never zero (guarded); readers
// poll the t-indexed data words directly until all nonzero.
__global__ __launch_bounds__(256) void lstm_rec_k(const __hip_bfloat16* __restrict__ Ut,  // [2][2048][512]
                                                  const __hip_bfloat16* __restrict__ xz,  // [dir][swg][t][2048]
                                                  __hip_bfloat16* __restrict__ ynext,     // [16][1024][1024], pre-zeroed
                                                  float* __restrict__ outf) {             // last layer or null
  extern __shared__ char smem[];
  uint4* uh = (uint4*)smem;                                 // 8192 x 16B
  __hip_bfloat16* hbuf = (__hip_bfloat16*)(smem + 131072);  // [16][528]
  float* zbuf = (float*)(smem + 147968);                    // [16][132]
  __hip_bfloat16* xbuf = (__hip_bfloat16*)(smem + 156416);  // [2048]
  int dir = blockIdx.x & 1;
  int swg = blockIdx.x >> 1;
  int u0 = swg * 32;
  int tid = threadIdx.x, lane = tid & 63, wv = tid >> 6;
  int quad = lane >> 4, l15 = lane & 15;
  const __hip_bfloat16* Ud = Ut + (size_t)dir * 2048 * 512;

  // fill LDS with Uh slice, pre-fragmented (same as R3)
#pragma unroll 4
  for (int i = 0; i < 32; ++i) {
    int slot = i * 256 + tid;
    int ls = slot & 63, kc = (slot >> 6) & 15, nt = slot >> 10;
    int n_g = (nt >> 1) * 512 + u0 + (nt & 1) * 16 + (ls & 15);
    int k = kc * 32 + (ls >> 4) * 8;
    uh[slot] = *(const uint4*)(Ud + (size_t)n_g * 512 + k);
  }
  __syncthreads();

  int nt0 = wv * 2, nt1 = wv * 2 + 1;
  int pb = tid >> 4, pj = (tid & 15) * 2;
  float c0 = 0.f, c1 = 0.f;

  int t0 = dir ? 1023 : 0;
  const uint4* xp0 = (const uint4*)(xz + ((size_t)(dir * 16 + swg) * 1024 + t0) * 2048) + tid;
  uint4 xcur = *xp0;

  for (int s = 0; s < 1024; ++s) {
    int t = dir ? (1023 - s) : s;
    // prefetch next step's xz (independent of the exchange; overlaps the poll)
    uint4 xnxt;
    if (s < 1023) {
      int tn = dir ? (1022 - s) : (s + 1);
      xnxt = *((const uint4*)(xz + ((size_t)(dir * 16 + swg) * 1024 + tn) * 2048) + tid);
    }
    f32x4 z0 = {}, z1 = {};
    if (s > 0) {
      int tprev = dir ? (t + 1) : (t - 1);
      // sentinel poll == coalesced h load: 64B/thread, retry words still zero.
      unsigned long long hv[8];
      const unsigned long long* gp[8];
#pragma unroll
      for (int i = 0; i < 4; ++i) {
        int v = i * 2048 + tid * 8;
        int b = v >> 9, col = v & 511;
        const unsigned long long* g =
            (const unsigned long long*)(ynext + ((size_t)b * 1024 + tprev) * 1024 + dir * 512 + col);
        gp[2 * i] = g;
        gp[2 * i + 1] = g + 1;
      }
#pragma unroll
      for (int i = 0; i < 8; ++i)
        hv[i] = __hip_atomic_load(gp[i], __ATOMIC_RELAXED, __HIP_MEMORY_SCOPE_AGENT);
      for (;;) {
        bool ok = true;
#pragma unroll
        for (int i = 0; i < 8; ++i)
          ok &= ((uint32_t)hv[i] != 0u) && ((uint32_t)(hv[i] >> 32) != 0u);
        if (ok) break;
#pragma unroll
        for (int i = 0; i < 8; ++i)
          if (((uint32_t)hv[i] == 0u) || ((uint32_t)(hv[i] >> 32) == 0u))
            hv[i] = __hip_atomic_load(gp[i], __ATOMIC_RELAXED, __HIP_MEMORY_SCOPE_AGENT);
      }
#pragma unroll
      for (int i = 0; i < 4; ++i) {
        int v = i * 2048 + tid * 8;
        int b = v >> 9, col = v & 511;
        unsigned long long* lp = (unsigned long long*)(hbuf + b * 528 + col);
        lp[0] = hv[2 * i];
        lp[1] = hv[2 * i + 1];
      }
      __syncthreads();
      // A-frags from LDS (b128, pitch 528: 16 bank-starts x 4 lanes) + MFMA
#pragma unroll
      for (int kc = 0; kc < 16; ++kc) {
        short8 afrag = *(const short8*)(hbuf + l15 * 528 + kc * 32 + quad * 8);
        z0 = __builtin_amdgcn_mfma_f32_16x16x32_bf16(afrag, as_short8(uh[(nt0 * 16 + kc) * 64 + lane]), z0, 0, 0, 0);
        z1 = __builtin_amdgcn_mfma_f32_16x16x32_bf16(afrag, as_short8(uh[(nt1 * 16 + kc) * 64 + lane]), z1, 0, 0, 0);
      }
    }
    // publish z to zbuf (pitch 132); stage xz chunk to xbuf
#pragma unroll
    for (int r = 0; r < 4; ++r) {
      int m = quad * 4 + r;
      zbuf[m * 132 + nt0 * 16 + l15] = z0[r];
      zbuf[m * 132 + nt1 * 16 + l15] = z1[r];
    }
    *(uint4*)(xbuf + tid * 8) = xcur;
    __syncthreads();
    // gates: i,f,g,o = sigmoid; c = f*c + i*g; h = o*sigmoid(c)
    const float* zb = zbuf + pb * 132;
    uint32_t xi = *(const uint32_t*)(xbuf + (0 * 16 + pb) * 32 + pj);
    uint32_t xf = *(const uint32_t*)(xbuf + (1 * 16 + pb) * 32 + pj);
    uint32_t xg = *(const uint32_t*)(xbuf + (2 * 16 + pb) * 32 + pj);
    uint32_t xo = *(const uint32_t*)(xbuf + (3 * 16 + pb) * 32 + pj);
    float i0 = sigf(zb[pj] + bflo(xi)),      i1 = sigf(zb[pj + 1] + bfhi(xi));
    float f0 = sigf(zb[32 + pj] + bflo(xf)), f1 = sigf(zb[32 + pj + 1] + bfhi(xf));
    float g0 = sigf(zb[64 + pj] + bflo(xg)), g1 = sigf(zb[64 + pj + 1] + bfhi(xg));
    float o0 = sigf(zb[96 + pj] + bflo(xo)), o1 = sigf(zb[96 + pj + 1] + bfhi(xo));
    c0 = f0 * c0 + i0 * g0;
    c1 = f1 * c1 + i1 * g1;
    float h0 = o0 * sigf(c0);
    float h1 = o1 * sigf(c1);
    size_t oidx = ((size_t)pb * 1024 + t) * 1024 + dir * 512 + u0 + pj;
    // pack with zero-guard: bump exact-zero bf16 halves to the min subnormal
    // (error <= 9e-41) so a packed word can never be 0 -> sentinel-safe.
    uint32_t ha = f2bfbits(h0); ha += (ha == 0u);
    uint32_t hb = f2bfbits(h1); hb += (hb == 0u);
    uint32_t hp = ha | (hb << 16);
    __hip_atomic_store((uint32_t*)(ynext + oidx), hp, __ATOMIC_RELAXED, __HIP_MEMORY_SCOPE_AGENT);
    if (outf) { outf[oidx] = h0; outf[oidx + 1] = h1; }
    __syncthreads();   // drains vmcnt: h stores globally visible before next poll
    xcur = xnxt;
  }
}

// ---------------------------------------------------------------------------
extern "C" void kernel_launch(void* const* d_in, const int* in_sizes, int n_in,
                              void* d_out, int out_size, void* d_ws, size_t ws_size,
                              hipStream_t stream) {
  const float* x  = (const float*)d_in[0];   // [16][1024][1024]
  const float* W  = (const float*)d_in[1];   // [5][2][1024][2048]
  const float* Uh = (const float*)d_in[2];   // [5][2][512][2048]
  const float* b  = (const float*)d_in[3];   // [5][2][2048]

  char* ws = (char*)d_ws;
  size_t off = 0;
  __hip_bfloat16* yA = (__hip_bfloat16*)(ws + off); off += (size_t)16 * 1024 * 1024 * 2;
  __hip_bfloat16* yB = (__hip_bfloat16*)(ws + off); off += (size_t)16 * 1024 * 1024 * 2;
  __hip_bfloat16* xz = (__hip_bfloat16*)(ws + off); off += (size_t)2 * 16 * 1024 * 2048 * 2;
  __hip_bfloat16* Wt = (__hip_bfloat16*)(ws + off); off += (size_t)2 * 2048 * 1024 * 2;
  __hip_bfloat16* Ut = (__hip_bfloat16*)(ws + off); off += (size_t)2 * 2048 * 512 * 2;

  f32_to_bf16_k<<<dim3(16384), dim3(256), 0, stream>>>(x, yA, 4194304);
  hipFuncSetAttribute(reinterpret_cast<const void*>(lstm_rec_k),
                      hipFuncAttributeMaxDynamicSharedMemorySize, 160512);
  for (int l = 0; l < 5; ++l) {
    transpose_bf16_k<<<dim3(16, 32, 2), dim3(256), 0, stream>>>(W + (size_t)l * 2 * 1024 * 2048, Wt, 1024);
    transpose_bf16_k<<<dim3(8, 32, 2),  dim3(256), 0, stream>>>(Uh + (size_t)l * 2 * 512 * 2048, Ut, 512);
    __hip_bfloat16* ycur = (l & 1) ? yB : yA;
    __hip_bfloat16* ynxt = (l & 1) ? yA : yB;
    // zero ynxt: sentinel protocol requires unwritten h words to read as 0.
    hipMemsetAsync(ynxt, 0, (size_t)16 * 1024 * 1024 * 2, stream);
    gemm_xz_k<<<dim3(128, 32), dim3(256), 0, stream>>>(ycur, Wt, b + (size_t)l * 2 * 2048, xz);
    lstm_rec_k<<<dim3(32), dim3(256), 160512, stream>>>(
        Ut, xz, ynxt, (l == 4) ? (float*)d_out : nullptr);
  }
}

// Round 9
// 13863.055 us; speedup vs baseline: 5.8761x; 1.0689x over previous
//
#include <hip/hip_runtime.h>
#include <hip/hip_bf16.h>
#include <stdint.h>

// ---------------------------------------------------------------------------
// Bidirectional 5-layer LSTM (all-sigmoid), B=16, T=1024, D=1024, U=512.
// R11 = byte-exact revert to the R3 champion (13.87 ms), closing the session.
// R3: sentinel-protocol recurrence exchange.
//   - ynext is zeroed per layer; h>0 always (c>0, o>0), so every packed h u32
//     is nonzero. Readers speculatively load the t-indexed h words (agent
//     scope) and retry while any u32 half is zero: the poll IS the data load.
//   - 1-ulp subnormal guard on packed h halves makes exact-zero impossible.
// Elements proven load-bearing by the R4-R10 failure ledger:
//   - serialize-then-poll: store -> __syncthreads vmcnt(0) drain -> THEN poll.
//     Any poll racing in-flight stores (R5 raw-barrier, R9 early-poll) LLC-
//     thrashes: WRITE_SIZE 3x, net regression.
//   - coalesced h rows: 16 contiguous lanes own each 64B h line (R8's
//     scattered 4B stores -> 6x HBM write traffic).
//   - 16 blocks/dir x 32 units topology (R6 alternation doubled traffic;
//     R7 XCD-local exchange hit L1 staleness).
//   - minimal live registers across the poll (R4's 32 live u64s spilled).
//   - LDS bank conflicts (1.68e7) are fully hidden under exchange latency:
//     fixing them (R10 pitch 528) cost 7% for zero critical-path gain.
// ---------------------------------------------------------------------------

typedef __attribute__((ext_vector_type(8))) short short8;
typedef __attribute__((ext_vector_type(4))) float f32x4;

union U128 { uint4 u; short8 s; };
static __device__ __forceinline__ short8 as_short8(uint4 v) { U128 x; x.u = v; return x.s; }

static __device__ __forceinline__ float sigf(float x) { return 1.0f / (1.0f + __expf(-x)); }

static __device__ __forceinline__ uint32_t f2bfbits(float f) {
  union { float f; uint32_t u; } x; x.f = f;
  return (x.u + 0x7fffu + ((x.u >> 16) & 1u)) >> 16;   // RNE; h in (0,1), no NaN
}
static __device__ __forceinline__ float bflo(uint32_t v) {
  union { uint32_t u; float f; } x; x.u = v << 16; return x.f;
}
static __device__ __forceinline__ float bfhi(uint32_t v) {
  union { uint32_t u; float f; } x; x.u = v & 0xffff0000u; return x.f;
}

// ---------------- x (fp32) -> bf16 ----------------
__global__ __launch_bounds__(256) void f32_to_bf16_k(const float* __restrict__ in,
                                                     __hip_bfloat16* __restrict__ out,
                                                     int n4) {
  int i = blockIdx.x * 256 + threadIdx.x;
  if (i < n4) {
    float4 v = ((const float4*)in)[i];
    uint32_t lo = f2bfbits(v.x) | (f2bfbits(v.y) << 16);
    uint32_t hi = f2bfbits(v.z) | (f2bfbits(v.w) << 16);
    ((uint2*)out)[i] = make_uint2(lo, hi);
  }
}

// ---------------- [2][R][2048] fp32 -> [2][2048][R] bf16 transpose ----------------
__global__ __launch_bounds__(256) void transpose_bf16_k(const float* __restrict__ in,
                                                        __hip_bfloat16* __restrict__ outp,
                                                        int R) {
  __shared__ float tile[64][65];
  int d = blockIdx.z;
  int k0 = blockIdx.x * 64;
  int c0 = blockIdx.y * 64;
  const float* inb = in + (size_t)d * R * 2048;
  __hip_bfloat16* ob = outp + (size_t)d * 2048 * R;
  int col = threadIdx.x & 63, rr = threadIdx.x >> 6;
#pragma unroll
  for (int i = 0; i < 16; ++i) {
    int r = rr + i * 4;
    tile[r][col] = inb[(size_t)(k0 + r) * 2048 + c0 + col];
  }
  __syncthreads();
#pragma unroll
  for (int i = 0; i < 16; ++i) {
    int r = rr + i * 4;
    ob[(size_t)(c0 + r) * R + k0 + col] = __float2bfloat16(tile[col][r]);
  }
}

// ---------------- xz GEMM: y[16384,1024] @ Wt[2][2048,1024]^T + b ----------------
// Output layout: xz[dir][swg(16)][t(1024)][q(4)][b(16)][j(32)]  (4KB per (dir,swg,t))
__global__ __launch_bounds__(256) void gemm_xz_k(const __hip_bfloat16* __restrict__ y,
                                                 const __hip_bfloat16* __restrict__ Wt,
                                                 const float* __restrict__ bias,
                                                 __hip_bfloat16* __restrict__ xz) {
  __shared__ uint4 Asl[8 * 2 * 64];
  __shared__ uint4 Bsl[8 * 2 * 64];
  int m0 = blockIdx.x * 128;
  int dir = blockIdx.y >> 4;
  int n0 = (blockIdx.y & 15) * 128;
  int tid = threadIdx.x, lane = tid & 63, wv = tid >> 6;
  int wm = wv & 1, wn = wv >> 1;
  const __hip_bfloat16* Wd = Wt + (size_t)dir * 2048 * 1024;
  f32x4 acc[4][4] = {};
  for (int kb = 0; kb < 1024; kb += 64) {
    __syncthreads();
#pragma unroll
    for (int i = 0; i < 4; ++i) {
      int slot = i * 256 + tid;
      int ln = slot & 63, kc = (slot >> 6) & 1, mt = slot >> 7;
      int row = mt * 16 + (ln & 15);
      int kk = kc * 32 + (ln >> 4) * 8;
      Asl[slot] = *(const uint4*)(y + (size_t)(m0 + row) * 1024 + kb + kk);
      Bsl[slot] = *(const uint4*)(Wd + (size_t)(n0 + row) * 1024 + kb + kk);
    }
    __syncthreads();
#pragma unroll
    for (int kc = 0; kc < 2; ++kc) {
      short8 af[4], bf[4];
#pragma unroll
      for (int i = 0; i < 4; ++i) {
        af[i] = as_short8(Asl[((wm * 4 + i) * 2 + kc) * 64 + lane]);
        bf[i] = as_short8(Bsl[((wn * 4 + i) * 2 + kc) * 64 + lane]);
      }
#pragma unroll
      for (int i = 0; i < 4; ++i)
#pragma unroll
        for (int j = 0; j < 4; ++j)
          acc[i][j] = __builtin_amdgcn_mfma_f32_16x16x32_bf16(af[i], bf[j], acc[i][j], 0, 0, 0);
    }
  }
  // epilogue: C/D layout col=lane&15, row=(lane>>4)*4+r  [m89-verified]
  int cq = lane >> 4, cn = lane & 15;
#pragma unroll
  for (int i = 0; i < 4; ++i)
#pragma unroll
    for (int j = 0; j < 4; ++j) {
      int n_g = n0 + (wn * 4 + j) * 16 + cn;
      int q = n_g >> 9, u = n_g & 511, swg = u >> 5, jj = u & 31;
      float bv = bias[dir * 2048 + n_g];
#pragma unroll
      for (int r = 0; r < 4; ++r) {
        int m = m0 + (wm * 4 + i) * 16 + cq * 4 + r;
        int b = m >> 10, t = m & 1023;
        size_t addr = (((size_t)(dir * 16 + swg) * 1024 + t) * 2048) + (q * 16 + b) * 32 + jj;
        xz[addr] = __float2bfloat16(acc[i][j][r] + bv);
      }
    }
}

// ---------------- persistent bidirectional recurrence ----------------
// 32 blocks: dir = blockIdx&1, slice = blockIdx>>1 (16 slices/dir, 32 u-cols).
// LDS: uh 128KB | hbuf 16x(512+8) bf16 = 16640B | zbuf 16x128 f32 = 8KB |
//      xbuf 2048 bf16 = 4KB  -> 160000 B total.
// Sentinel exchange: ynext pre-zeroed; h words never zero (guarded); readers
// poll the t-indexed data words directly until all nonzero.
__global__ __launch_bounds__(256) void lstm_rec_k(const __hip_bfloat16* __restrict__ Ut,  // [2][2048][512]
                                                  const __hip_bfloat16* __restrict__ xz,  // [dir][swg][t][2048]
                                                  __hip_bfloat16* __restrict__ ynext,     // [16][1024][1024], pre-zeroed
                                                  float* __restrict__ outf) {             // last layer or null
  extern __shared__ char smem[];
  uint4* uh = (uint4*)smem;                          // 8192 x 16B
  __hip_bfloat16* hbuf = (__hip_bfloat16*)(smem + 131072);  // [16][520]
  float* zbuf = (float*)(smem + 147712);             // [16][128]
  __hip_bfloat16* xbuf = (__hip_bfloat16*)(smem + 155904);  // [2048]
  int dir = blockIdx.x & 1;
  int swg = blockIdx.x >> 1;
  int u0 = swg * 32;
  int tid = threadIdx.x, lane = tid & 63, wv = tid >> 6;
  int quad = lane >> 4, l15 = lane & 15;
  const __hip_bfloat16* Ud = Ut + (size_t)dir * 2048 * 512;

  // fill LDS with Uh slice, pre-fragmented (same as R1/R2)
#pragma unroll 4
  for (int i = 0; i < 32; ++i) {
    int slot = i * 256 + tid;
    int ls = slot & 63, kc = (slot >> 6) & 15, nt = slot >> 10;
    int n_g = (nt >> 1) * 512 + u0 + (nt & 1) * 16 + (ls & 15);
    int k = kc * 32 + (ls >> 4) * 8;
    uh[slot] = *(const uint4*)(Ud + (size_t)n_g * 512 + k);
  }
  __syncthreads();

  int nt0 = wv * 2, nt1 = wv * 2 + 1;
  int pb = tid >> 4, pj = (tid & 15) * 2;
  float c0 = 0.f, c1 = 0.f;

  int t0 = dir ? 1023 : 0;
  const uint4* xp0 = (const uint4*)(xz + ((size_t)(dir * 16 + swg) * 1024 + t0) * 2048) + tid;
  uint4 xcur = *xp0;

  for (int s = 0; s < 1024; ++s) {
    int t = dir ? (1023 - s) : s;
    // prefetch next step's xz (independent of the exchange; overlaps the poll)
    uint4 xnxt;
    if (s < 1023) {
      int tn = dir ? (1022 - s) : (s + 1);
      xnxt = *((const uint4*)(xz + ((size_t)(dir * 16 + swg) * 1024 + tn) * 2048) + tid);
    }
    f32x4 z0 = {}, z1 = {};
    if (s > 0) {
      int tprev = dir ? (t + 1) : (t - 1);
      // sentinel poll == coalesced h load: 64B/thread, retry words still zero.
      unsigned long long hv[8];
      const unsigned long long* gp[8];
#pragma unroll
      for (int i = 0; i < 4; ++i) {
        int v = i * 2048 + tid * 8;
        int b = v >> 9, col = v & 511;
        const unsigned long long* g =
            (const unsigned long long*)(ynext + ((size_t)b * 1024 + tprev) * 1024 + dir * 512 + col);
        gp[2 * i] = g;
        gp[2 * i + 1] = g + 1;
      }
#pragma unroll
      for (int i = 0; i < 8; ++i)
        hv[i] = __hip_atomic_load(gp[i], __ATOMIC_RELAXED, __HIP_MEMORY_SCOPE_AGENT);
      for (;;) {
        bool ok = true;
#pragma unroll
        for (int i = 0; i < 8; ++i)
          ok &= ((uint32_t)hv[i] != 0u) && ((uint32_t)(hv[i] >> 32) != 0u);
        if (ok) break;
#pragma unroll
        for (int i = 0; i < 8; ++i)
          if (((uint32_t)hv[i] == 0u) || ((uint32_t)(hv[i] >> 32) == 0u))
            hv[i] = __hip_atomic_load(gp[i], __ATOMIC_RELAXED, __HIP_MEMORY_SCOPE_AGENT);
      }
#pragma unroll
      for (int i = 0; i < 4; ++i) {
        int v = i * 2048 + tid * 8;
        int b = v >> 9, col = v & 511;
        unsigned long long* lp = (unsigned long long*)(hbuf + b * 520 + col);
        lp[0] = hv[2 * i];
        lp[1] = hv[2 * i + 1];
      }
      __syncthreads();
      // A-frags from LDS (b128, 2-way bank alias = free) + MFMA
#pragma unroll
      for (int kc = 0; kc < 16; ++kc) {
        short8 afrag = *(const short8*)(hbuf + l15 * 520 + kc * 32 + quad * 8);
        z0 = __builtin_amdgcn_mfma_f32_16x16x32_bf16(afrag, as_short8(uh[(nt0 * 16 + kc) * 64 + lane]), z0, 0, 0, 0);
        z1 = __builtin_amdgcn_mfma_f32_16x16x32_bf16(afrag, as_short8(uh[(nt1 * 16 + kc) * 64 + lane]), z1, 0, 0, 0);
      }
    }
    // publish z to zbuf; stage xz chunk to xbuf
#pragma unroll
    for (int r = 0; r < 4; ++r) {
      int m = quad * 4 + r;
      zbuf[m * 128 + nt0 * 16 + l15] = z0[r];
      zbuf[m * 128 + nt1 * 16 + l15] = z1[r];
    }
    *(uint4*)(xbuf + tid * 8) = xcur;
    __syncthreads();
    // gates: i,f,g,o = sigmoid; c = f*c + i*g; h = o*sigmoid(c)
    const float* zb = zbuf + pb * 128;
    uint32_t xi = *(const uint32_t*)(xbuf + (0 * 16 + pb) * 32 + pj);
    uint32_t xf = *(const uint32_t*)(xbuf + (1 * 16 + pb) * 32 + pj);
    uint32_t xg = *(const uint32_t*)(xbuf + (2 * 16 + pb) * 32 + pj);
    uint32_t xo = *(const uint32_t*)(xbuf + (3 * 16 + pb) * 32 + pj);
    float i0 = sigf(zb[pj] + bflo(xi)),      i1 = sigf(zb[pj + 1] + bfhi(xi));
    float f0 = sigf(zb[32 + pj] + bflo(xf)), f1 = sigf(zb[32 + pj + 1] + bfhi(xf));
    float g0 = sigf(zb[64 + pj] + bflo(xg)), g1 = sigf(zb[64 + pj + 1] + bfhi(xg));
    float o0 = sigf(zb[96 + pj] + bflo(xo)), o1 = sigf(zb[96 + pj + 1] + bfhi(xo));
    c0 = f0 * c0 + i0 * g0;
    c1 = f1 * c1 + i1 * g1;
    float h0 = o0 * sigf(c0);
    float h1 = o1 * sigf(c1);
    size_t oidx = ((size_t)pb * 1024 + t) * 1024 + dir * 512 + u0 + pj;
    // pack with zero-guard: bump exact-zero bf16 halves to the min subnormal
    // (error <= 9e-41) so a packed word can never be 0 -> sentinel-safe.
    uint32_t ha = f2bfbits(h0); ha += (ha == 0u);
    uint32_t hb = f2bfbits(h1); hb += (hb == 0u);
    uint32_t hp = ha | (hb << 16);
    __hip_atomic_store((uint32_t*)(ynext + oidx), hp, __ATOMIC_RELAXED, __HIP_MEMORY_SCOPE_AGENT);
    if (outf) { outf[oidx] = h0; outf[oidx + 1] = h1; }
    __syncthreads();   // drains vmcnt: h stores on their way to LLC; keeps block lockstep
    xcur = xnxt;
  }
}

// ---------------------------------------------------------------------------
extern "C" void kernel_launch(void* const* d_in, const int* in_sizes, int n_in,
                              void* d_out, int out_size, void* d_ws, size_t ws_size,
                              hipStream_t stream) {
  const float* x  = (const float*)d_in[0];   // [16][1024][1024]
  const float* W  = (const float*)d_in[1];   // [5][2][1024][2048]
  const float* Uh = (const float*)d_in[2];   // [5][2][512][2048]
  const float* b  = (const float*)d_in[3];   // [5][2][2048]

  char* ws = (char*)d_ws;
  size_t off = 0;
  __hip_bfloat16* yA = (__hip_bfloat16*)(ws + off); off += (size_t)16 * 1024 * 1024 * 2;
  __hip_bfloat16* yB = (__hip_bfloat16*)(ws + off); off += (size_t)16 * 1024 * 1024 * 2;
  __hip_bfloat16* xz = (__hip_bfloat16*)(ws + off); off += (size_t)2 * 16 * 1024 * 2048 * 2;
  __hip_bfloat16* Wt = (__hip_bfloat16*)(ws + off); off += (size_t)2 * 2048 * 1024 * 2;
  __hip_bfloat16* Ut = (__hip_bfloat16*)(ws + off); off += (size_t)2 * 2048 * 512 * 2;

  f32_to_bf16_k<<<dim3(16384), dim3(256), 0, stream>>>(x, yA, 4194304);
  hipFuncSetAttribute(reinterpret_cast<const void*>(lstm_rec_k),
                      hipFuncAttributeMaxDynamicSharedMemorySize, 160000);
  for (int l = 0; l < 5; ++l) {
    transpose_bf16_k<<<dim3(16, 32, 2), dim3(256), 0, stream>>>(W + (size_t)l * 2 * 1024 * 2048, Wt, 1024);
    transpose_bf16_k<<<dim3(8, 32, 2),  dim3(256), 0, stream>>>(Uh + (size_t)l * 2 * 512 * 2048, Ut, 512);
    __hip_bfloat16* ycur = (l & 1) ? yB : yA;
    __hip_bfloat16* ynxt = (l & 1) ? yA : yB;
    // zero ynxt: sentinel protocol requires unwritten h words to read as 0.
    // ynxt is dead since gemm(l-1) consumed it; ~32MB memset is ~10us.
    hipMemsetAsync(ynxt, 0, (size_t)16 * 1024 * 1024 * 2, stream);
    gemm_xz_k<<<dim3(128, 32), dim3(256), 0, stream>>>(ycur, Wt, b + (size_t)l * 2 * 2048, xz);
    lstm_rec_k<<<dim3(32), dim3(256), 160000, stream>>>(
        Ut, xz, ynxt, (l == 4) ? (float*)d_out : nullptr);
  }
}